// Round 4
// baseline (321.029 us; speedup 1.0000x reference)
//
#include <hip/hip_runtime.h>
#include <math.h>

#define HEADS 4
#define BATCH 8
#define SEQ   1024
#define CH    256
#define DH    64
#define RB    16          // q rows per block
#define NTHR  512         // 8 waves
#define SSTR  1032        // Sraw row stride in u16 (2064 B, 16B-mult)

typedef float  floatx4  __attribute__((ext_vector_type(4)));
typedef float  floatx2  __attribute__((ext_vector_type(2)));
typedef short  shortx8  __attribute__((ext_vector_type(8)));

__device__ __forceinline__ unsigned short f2bf(float f) {
    unsigned u = __float_as_uint(f);
    unsigned r = u + 0x7FFFu + ((u >> 16) & 1u);   // RNE; -inf stays -inf
    return (unsigned short)(r >> 16);
}
__device__ __forceinline__ float bf2f(unsigned short h) {
    return __uint_as_float(((unsigned)h) << 16);
}
__device__ __forceinline__ shortx8 pack8(float4 a, float4 b) {
    shortx8 r;
    r[0] = (short)f2bf(a.x); r[1] = (short)f2bf(a.y);
    r[2] = (short)f2bf(a.z); r[3] = (short)f2bf(a.w);
    r[4] = (short)f2bf(b.x); r[5] = (short)f2bf(b.y);
    r[6] = (short)f2bf(b.z); r[7] = (short)f2bf(b.w);
    return r;
}

// ---- prologue: one-time staging into workspace.
// qb/kb: bf16 [B,N,C].  vt: bf16 V transposed per head [b][h][d][n].
// pm: bit-packed mask, PM[b][row4][c0] u32; byte r = bits mc=0..7 for
//     row=row4*4+r, col=mc*128+c0.  One u32 = one main-kernel thread's mask.
__global__ __launch_bounds__(256)
void prep(const float* __restrict__ q, const float* __restrict__ k,
          const float* __restrict__ v, const void* __restrict__ maskp,
          unsigned short* __restrict__ qb, unsigned short* __restrict__ kb,
          unsigned short* __restrict__ vt, unsigned* __restrict__ pm)
{
    __shared__ unsigned short tl[64][68];
    const int t = threadIdx.x;
    const int bid = blockIdx.x;
    if (bid < 2048) {                       // q (0..1023) / k (1024..2047) convert
        const float* src = (bid < 1024) ? q : k;
        unsigned short* dst = (bid < 1024) ? qb : kb;
        size_t idx = (size_t)(bid & 1023) * 2048 + (size_t)t * 8;
        float4 a = *(const float4*)(src + idx);
        float4 b = *(const float4*)(src + idx + 4);
        *(shortx8*)(dst + idx) = pack8(a, b);
        return;
    }
    if (bid < 2560) {
        // V transpose-convert: block = (b, h, 64-row n-tile)
        const int vb = bid - 2048;
        const int nt = vb & 15, h = (vb >> 4) & 3, b = vb >> 6;
        const int n0 = nt * 64;
        const float* vsrc = v + ((size_t)(b * SEQ + n0)) * CH + h * DH;
        #pragma unroll
        for (int it = 0; it < 4; ++it) {
            int fid = it * 256 + t;
            int n = fid >> 4, cc = (fid & 15) * 4;
            float4 x = *(const float4*)(vsrc + (size_t)n * CH + cc);
            tl[n][cc]     = f2bf(x.x);
            tl[n][cc + 1] = f2bf(x.y);
            tl[n][cc + 2] = f2bf(x.z);
            tl[n][cc + 3] = f2bf(x.w);
        }
        __syncthreads();
        unsigned short* vout = vt + ((size_t)((b * HEADS + h) * DH)) * SEQ + n0;
        #pragma unroll
        for (int it = 0; it < 2; ++it) {
            int cid = it * 256 + t;
            int d = cid >> 3, nc = cid & 7;
            shortx8 r;
            #pragma unroll
            for (int j = 0; j < 8; ++j) r[j] = (short)tl[nc * 8 + j][d];
            *(shortx8*)(vout + (size_t)d * SEQ + nc * 8) = r;
        }
        return;
    }
    // ---- mask pack: block = (b, row8); threads = sub(2) x c0(128) ----
    const int vb2 = bid - 2560;              // 0..1023
    const int b = vb2 >> 7, row8 = vb2 & 127;
    const int sub = t >> 7, c0 = t & 127;
    const int row4 = row8 * 2 + sub;
    // dtype detect: int32 bool => misaligned high bytes all 0 in leading 4KB
    int fl;
    {
        const unsigned* mw = (const unsigned*)maskp;
        const int lane = t & 63;
        int found = 0;
        #pragma unroll
        for (int j = 0; j < 16; ++j)
            if (mw[lane * 16 + j] & 0xFFFFFF00u) found = 1;
        fl = (__ballot(found != 0) != 0ULL) ? 1 : 0;   // 1 => byte mask
    }
    const unsigned char* m8  = (const unsigned char*)maskp;
    const int*           m32 = (const int*)maskp;
    unsigned u = 0;
    #pragma unroll
    for (int r = 0; r < 4; ++r) {
        #pragma unroll
        for (int mc = 0; mc < 8; ++mc) {
            size_t idx = ((size_t)(b * SEQ + row4 * 4 + r)) * SEQ + mc * 128 + c0;
            int mk = fl ? (int)m8[idx] : m32[idx];
            u |= (mk ? 1u : 0u) << (r * 8 + mc);
        }
    }
    pm[((b * 256 + row4) * 128) + c0] = u;
}

// One (b, n-tile, head) per block, 2048 blocks. Head-siblings of a
// (b, n-tile) are 8 bids apart: same XCD + temporally adjacent => the shared
// dis tile is HBM-fetched once, L2-hit 3x. All 32 dis values + the packed
// mask u32 are loaded into registers UP FRONT: one latency window instead of
// four (the r3 kernel was latency-bound in pass 1, not bandwidth-bound).
__global__ __launch_bounds__(NTHR, 6)
void attn_mfma(const unsigned short* __restrict__ qb,
               const unsigned short* __restrict__ kbf,
               const unsigned short* __restrict__ vt,
               const unsigned* __restrict__ pm,
               const float* __restrict__ dis, float* __restrict__ out,
               float* __restrict__ pout)
{
    __shared__ unsigned short Sraw[RB][SSTR];    // 33 KB: raw scores -> exp
    __shared__ float Opart[RB][65];              // 4.2 KB partial O (pad 65)
    __shared__ float invs[RB];

    const int t   = threadIdx.x;
    const int bid = blockIdx.x;
    const int b   = bid & (BATCH - 1);     // XCD-pinned batch
    const int h   = (bid >> 3) & (HEADS - 1);
    const int n0  = (bid >> 5) * RB;

    const int lane = t & 63;
    const int w    = t >> 6;       // wave 0..7
    const int ln   = lane & 15;    // fragment m / n index
    const int qd   = lane >> 4;    // quad -> k-group / D row group

    // ---- issue ALL dis loads first (32 independent HBM loads in flight) ----
    float dreg[32];
    {
        const size_t dib0 = ((size_t)(b * SEQ + n0 + qd * 4)) * SEQ + w * 16 + ln;
        #pragma unroll
        for (int mc = 0; mc < 8; ++mc) {
            #pragma unroll
            for (int r = 0; r < 4; ++r)
                dreg[mc * 4 + r] = dis[dib0 + (size_t)r * SEQ + mc * 128];
        }
    }
    // packed mask: one u32 covers this thread's 32 scores
    const unsigned mb = pm[((b * 256 + (n0 >> 2) + qd) * 128) + w * 16 + ln];

    // ---- Q A-frags: two aligned 16B loads (pre-converted bf16) ----
    const unsigned short* qrow = qb + ((size_t)(b * SEQ + n0 + ln)) * CH + h * DH;
    shortx8 aq0 = *(const shortx8*)(qrow + qd * 8);
    shortx8 aq1 = *(const shortx8*)(qrow + 32 + qd * 8);

    const unsigned short* kbase = kbf + ((size_t)(b * SEQ)) * CH + h * DH;
    const unsigned short* vbase = vt + ((size_t)((b * HEADS + h) * DH)) * SEQ;

    // ---- Pass 1: S = mask ? -inf : (Q K^T + dis)/8 -> bf16 LDS ----
    #pragma unroll 2
    for (int mc = 0; mc < 8; ++mc) {
        const int mg = mc * 128 + w * 16 + ln;        // score col == K row
        const unsigned short* krow = kbase + (size_t)mg * CH;  // L2-resident
        shortx8 b0 = *(const shortx8*)(krow + qd * 8);
        shortx8 b1 = *(const shortx8*)(krow + 32 + qd * 8);
        floatx4 acc = {0.f, 0.f, 0.f, 0.f};
        acc = __builtin_amdgcn_mfma_f32_16x16x32_bf16(aq0, b0, acc, 0, 0, 0);
        acc = __builtin_amdgcn_mfma_f32_16x16x32_bf16(aq1, b1, acc, 0, 0, 0);
        #pragma unroll
        for (int r = 0; r < 4; ++r) {                 // D: col=ln, row=qd*4+r
            float sc = ((mb >> (r * 8 + mc)) & 1u)
                           ? -INFINITY
                           : (acc[r] + dreg[mc * 4 + r]) * 0.125f;
            Sraw[qd * 4 + r][mg] = f2bf(sc);
        }
    }
    __syncthreads();

    // ---- Pass 2: softmax per row (32 threads/row), exp stored in-place ----
    {
        const int r = t >> 5, l = t & 31;
        float mx = -INFINITY;
        #pragma unroll
        for (int j = 0; j < 4; ++j) {
            shortx8 sv = *(const shortx8*)&Sraw[r][j * 256 + l * 8];
            #pragma unroll
            for (int e = 0; e < 8; ++e) mx = fmaxf(mx, bf2f((unsigned short)sv[e]));
        }
        #pragma unroll
        for (int off = 16; off; off >>= 1) mx = fmaxf(mx, __shfl_xor(mx, off, 32));
        float sum = 0.f;
        #pragma unroll
        for (int j = 0; j < 4; ++j) {
            shortx8 sv = *(const shortx8*)&Sraw[r][j * 256 + l * 8];
            shortx8 ev;
            #pragma unroll
            for (int e = 0; e < 8; ++e) {
                float x = __expf(bf2f((unsigned short)sv[e]) - mx);  // exp(-inf)=0
                sum += x;
                ev[e] = (short)f2bf(x);
            }
            *(shortx8*)&Sraw[r][j * 256 + l * 8] = ev;
        }
        #pragma unroll
        for (int off = 16; off; off >>= 1) sum += __shfl_xor(sum, off, 32);
        if (l == 0) invs[r] = 1.0f / sum;
    }
    __syncthreads();

    // ---- Pass 3: O = (E V) * inv. m-range split across wave halves. ----
    // Flattened + unroll 4: >=4 V loads in flight against the MFMA chain.
    const int hm = w >> 2;            // m-half 0/1
    const int c  = (w & 3) * 16;      // output col slice
    floatx4 acco = {0.f, 0.f, 0.f, 0.f};
    const unsigned short* vcol = vbase + (size_t)(c + ln) * SEQ;
    #pragma unroll 4
    for (int it = 0; it < 16; ++it) {
        const int kk = hm * 512 + (it >> 1) * 64 + (it & 1) * 32 + qd * 8;
        shortx8 af  = *(const shortx8*)&Sraw[ln][kk];     // A[m=ln][k]
        shortx8 bfv = *(const shortx8*)(vcol + kk);       // B[k][n=c+ln]
        acco = __builtin_amdgcn_mfma_f32_16x16x32_bf16(af, bfv, acco, 0, 0, 0);
    }

    // ---- normalized p_attn writes overlap pass-3 latency (never re-read) ----
    {
        float* prow = pout + ((size_t)((h * BATCH + b) * SEQ + n0)) * SEQ;
        #pragma unroll
        for (int i = 0; i < RB; ++i) {
            const float inv = invs[i];
            unsigned pk = *(const unsigned*)&Sraw[i][t * 2];
            floatx2 pv = { bf2f((unsigned short)(pk & 0xFFFFu)) * inv,
                           bf2f((unsigned short)(pk >> 16)) * inv };
            __builtin_nontemporal_store(
                pv, (floatx2*)(prow + (size_t)i * SEQ + t * 2));
        }
    }

    if (hm == 1) {
        #pragma unroll
        for (int r = 0; r < 4; ++r) Opart[qd * 4 + r][c + ln] = acco[r];
    }
    __syncthreads();
    if (hm == 0) {
        #pragma unroll
        for (int r = 0; r < 4; ++r) {
            int row = qd * 4 + r;
            float ov = (acco[r] + Opart[row][c + ln]) * invs[row];
            __builtin_nontemporal_store(
                ov, out + ((size_t)(b * SEQ + n0 + row)) * CH + h * DH + c + ln);
        }
    }
}

extern "C" void kernel_launch(void* const* d_in, const int* in_sizes, int n_in,
                              void* d_out, int out_size, void* d_ws, size_t ws_size,
                              hipStream_t stream) {
    const float* q    = (const float*)d_in[0];
    const float* k    = (const float*)d_in[1];
    const float* v    = (const float*)d_in[2];
    const void*  mask = d_in[3];
    const float* dis  = (const float*)d_in[4];
    float* out  = (float*)d_out;
    float* pout = out + (size_t)BATCH * SEQ * CH;   // p_attn after out

    // workspace: qb | kb | vt (each 2M bf16 = 4 MB) | pm (1 MB) => 13 MB
    unsigned short* qb  = (unsigned short*)d_ws;
    unsigned short* kbw = qb  + (size_t)BATCH * SEQ * CH;
    unsigned short* vtw = kbw + (size_t)BATCH * SEQ * CH;
    unsigned*       pmw = (unsigned*)(vtw + (size_t)BATCH * SEQ * CH);
    (void)ws_size;

    prep<<<3584, 256, 0, stream>>>(q, k, v, mask, qb, kbw, vtw, pmw);
    attn_mfma<<<HEADS * BATCH * (SEQ / RB), NTHR, 0, stream>>>(
        qb, kbw, vtw, pmw, dis, out, pout);
}

// Round 6
// 276.938 us; speedup vs baseline: 1.1592x; 1.1592x over previous
//
#include <hip/hip_runtime.h>
#include <math.h>

#define HEADS 4
#define BATCH 8
#define SEQ   1024
#define CH    256
#define DH    64
#define RB    16          // q rows per block
#define NTHR  512         // 8 waves
#define SSTR  1032        // Sraw row stride in u16 (2064 B, 16B-mult)

typedef float  floatx4  __attribute__((ext_vector_type(4)));
typedef float  floatx2  __attribute__((ext_vector_type(2)));
typedef short  shortx8  __attribute__((ext_vector_type(8)));

__device__ __forceinline__ unsigned short f2bf(float f) {
    unsigned u = __float_as_uint(f);
    unsigned r = u + 0x7FFFu + ((u >> 16) & 1u);   // RNE; -inf stays -inf
    return (unsigned short)(r >> 16);
}
__device__ __forceinline__ float bf2f(unsigned short h) {
    return __uint_as_float(((unsigned)h) << 16);
}
__device__ __forceinline__ shortx8 pack8(float4 a, float4 b) {
    shortx8 r;
    r[0] = (short)f2bf(a.x); r[1] = (short)f2bf(a.y);
    r[2] = (short)f2bf(a.z); r[3] = (short)f2bf(a.w);
    r[4] = (short)f2bf(b.x); r[5] = (short)f2bf(b.y);
    r[6] = (short)f2bf(b.z); r[7] = (short)f2bf(b.w);
    return r;
}

// ---- prologue: one-time staging into workspace.
// qb/kb: bf16 [B,N,C].  vt: bf16 V transposed per head [b][h][d][n].
// pm: bit-packed mask, PM[b][row4][c0] u32; byte r = bits mc=0..7 for
//     row=row4*4+r, col=mc*128+c0.  One u32 = one main-kernel thread's mask.
__global__ __launch_bounds__(256)
void prep(const float* __restrict__ q, const float* __restrict__ k,
          const float* __restrict__ v, const void* __restrict__ maskp,
          unsigned short* __restrict__ qb, unsigned short* __restrict__ kb,
          unsigned short* __restrict__ vt, unsigned* __restrict__ pm)
{
    __shared__ unsigned short tl[64][68];
    const int t = threadIdx.x;
    const int bid = blockIdx.x;
    if (bid < 2048) {                       // q (0..1023) / k (1024..2047) convert
        const float* src = (bid < 1024) ? q : k;
        unsigned short* dst = (bid < 1024) ? qb : kb;
        size_t idx = (size_t)(bid & 1023) * 2048 + (size_t)t * 8;
        float4 a = *(const float4*)(src + idx);
        float4 b = *(const float4*)(src + idx + 4);
        *(shortx8*)(dst + idx) = pack8(a, b);
        return;
    }
    if (bid < 2560) {
        // V transpose-convert: block = (b, h, 64-row n-tile)
        const int vb = bid - 2048;
        const int nt = vb & 15, h = (vb >> 4) & 3, b = vb >> 6;
        const int n0 = nt * 64;
        const float* vsrc = v + ((size_t)(b * SEQ + n0)) * CH + h * DH;
        #pragma unroll
        for (int it = 0; it < 4; ++it) {
            int fid = it * 256 + t;
            int n = fid >> 4, cc = (fid & 15) * 4;
            float4 x = *(const float4*)(vsrc + (size_t)n * CH + cc);
            tl[n][cc]     = f2bf(x.x);
            tl[n][cc + 1] = f2bf(x.y);
            tl[n][cc + 2] = f2bf(x.z);
            tl[n][cc + 3] = f2bf(x.w);
        }
        __syncthreads();
        unsigned short* vout = vt + ((size_t)((b * HEADS + h) * DH)) * SEQ + n0;
        #pragma unroll
        for (int it = 0; it < 2; ++it) {
            int cid = it * 256 + t;
            int d = cid >> 3, nc = cid & 7;
            shortx8 r;
            #pragma unroll
            for (int j = 0; j < 8; ++j) r[j] = (short)tl[nc * 8 + j][d];
            *(shortx8*)(vout + (size_t)d * SEQ + nc * 8) = r;
        }
        return;
    }
    // ---- mask pack: block = (b, row8); threads = sub(2) x c0(128) ----
    const int vb2 = bid - 2560;              // 0..1023
    const int b = vb2 >> 7, row8 = vb2 & 127;
    const int sub = t >> 7, c0 = t & 127;
    const int row4 = row8 * 2 + sub;
    // dtype detect: int32 bool => misaligned high bytes all 0 in leading 4KB
    int fl;
    {
        const unsigned* mw = (const unsigned*)maskp;
        const int lane = t & 63;
        int found = 0;
        #pragma unroll
        for (int j = 0; j < 16; ++j)
            if (mw[lane * 16 + j] & 0xFFFFFF00u) found = 1;
        fl = (__ballot(found != 0) != 0ULL) ? 1 : 0;   // 1 => byte mask
    }
    const unsigned char* m8  = (const unsigned char*)maskp;
    const int*           m32 = (const int*)maskp;
    unsigned u = 0;
    #pragma unroll
    for (int r = 0; r < 4; ++r) {
        #pragma unroll
        for (int mc = 0; mc < 8; ++mc) {
            size_t idx = ((size_t)(b * SEQ + row4 * 4 + r)) * SEQ + mc * 128 + c0;
            int mk = fl ? (int)m8[idx] : m32[idx];
            u |= (mk ? 1u : 0u) << (r * 8 + mc);
        }
    }
    pm[((b * 256 + row4) * 128) + c0] = u;
}

// One (b, n-tile, head) per block, 2048 blocks. Head-siblings of a
// (b, n-tile) are 8 bids apart: same XCD + temporally adjacent => shared dis
// tile fetched from HBM once, L2-hit 3x.  Latency-floor fixes this round:
// deeper pass-1 load pipelining (unroll 4), dual-accumulator pass 3, and all
// global stores moved AFTER the last barrier so no barrier waits on store
// drain.  NO min-waves launch-bounds clause (r4's 6-wave clause spilled
// dreg to scratch: VGPR 32 + 130 MB scratch writes).
__global__ __launch_bounds__(NTHR)
void attn_mfma(const unsigned short* __restrict__ qb,
               const unsigned short* __restrict__ kbf,
               const unsigned short* __restrict__ vt,
               const unsigned* __restrict__ pm,
               const float* __restrict__ dis, float* __restrict__ out,
               float* __restrict__ pout)
{
    __shared__ unsigned short Sraw[RB][SSTR];    // 33 KB: raw scores -> exp
    __shared__ float Opart[RB][65];              // 4.2 KB partial O (pad 65)
    __shared__ float invs[RB];

    const int t   = threadIdx.x;
    const int bid = blockIdx.x;
    const int b   = bid & (BATCH - 1);     // XCD-pinned batch
    const int h   = (bid >> 3) & (HEADS - 1);
    const int n0  = (bid >> 5) * RB;

    const int lane = t & 63;
    const int w    = t >> 6;       // wave 0..7
    const int ln   = lane & 15;    // fragment m / n index
    const int qd   = lane >> 4;    // quad -> k-group / D row group

    // packed mask: one u32 covers this thread's 32 scores (issue first: HBM)
    const unsigned mb = pm[((b * 256 + (n0 >> 2) + qd) * 128) + w * 16 + ln];

    // ---- Q A-frags: two aligned 16B loads (pre-converted bf16) ----
    const unsigned short* qrow = qb + ((size_t)(b * SEQ + n0 + ln)) * CH + h * DH;
    shortx8 aq0 = *(const shortx8*)(qrow + qd * 8);
    shortx8 aq1 = *(const shortx8*)(qrow + 32 + qd * 8);

    const unsigned short* kbase = kbf + ((size_t)(b * SEQ)) * CH + h * DH;
    const unsigned short* vbase = vt + ((size_t)((b * HEADS + h) * DH)) * SEQ;
    const size_t dib0 = ((size_t)(b * SEQ + n0 + qd * 4)) * SEQ + w * 16 + ln;

    // ---- Pass 1: S = mask ? -inf : (Q K^T + dis)/8 -> bf16 LDS ----
    // unroll 4: ~4 iterations of dis(HBM)/K(L2) loads in flight.
    #pragma unroll 4
    for (int mc = 0; mc < 8; ++mc) {
        const int mg = mc * 128 + w * 16 + ln;        // score col == K row
        const unsigned short* krow = kbase + (size_t)mg * CH;  // L2-resident
        shortx8 b0 = *(const shortx8*)(krow + qd * 8);
        shortx8 b1 = *(const shortx8*)(krow + 32 + qd * 8);
        float dv0 = dis[dib0 + mc * 128];
        float dv1 = dis[dib0 + (size_t)1 * SEQ + mc * 128];
        float dv2 = dis[dib0 + (size_t)2 * SEQ + mc * 128];
        float dv3 = dis[dib0 + (size_t)3 * SEQ + mc * 128];
        floatx4 acc = {0.f, 0.f, 0.f, 0.f};
        acc = __builtin_amdgcn_mfma_f32_16x16x32_bf16(aq0, b0, acc, 0, 0, 0);
        acc = __builtin_amdgcn_mfma_f32_16x16x32_bf16(aq1, b1, acc, 0, 0, 0);
        float sc0 = ((mb >> (0 * 8 + mc)) & 1u) ? -INFINITY : (acc[0] + dv0) * 0.125f;
        float sc1 = ((mb >> (1 * 8 + mc)) & 1u) ? -INFINITY : (acc[1] + dv1) * 0.125f;
        float sc2 = ((mb >> (2 * 8 + mc)) & 1u) ? -INFINITY : (acc[2] + dv2) * 0.125f;
        float sc3 = ((mb >> (3 * 8 + mc)) & 1u) ? -INFINITY : (acc[3] + dv3) * 0.125f;
        Sraw[qd * 4 + 0][mg] = f2bf(sc0);
        Sraw[qd * 4 + 1][mg] = f2bf(sc1);
        Sraw[qd * 4 + 2][mg] = f2bf(sc2);
        Sraw[qd * 4 + 3][mg] = f2bf(sc3);
    }
    __syncthreads();

    // ---- Pass 2: softmax per row (32 threads/row), exp stored in-place ----
    {
        const int r = t >> 5, l = t & 31;
        float mx = -INFINITY;
        #pragma unroll
        for (int j = 0; j < 4; ++j) {
            shortx8 sv = *(const shortx8*)&Sraw[r][j * 256 + l * 8];
            #pragma unroll
            for (int e = 0; e < 8; ++e) mx = fmaxf(mx, bf2f((unsigned short)sv[e]));
        }
        #pragma unroll
        for (int off = 16; off; off >>= 1) mx = fmaxf(mx, __shfl_xor(mx, off, 32));
        float sum = 0.f;
        #pragma unroll
        for (int j = 0; j < 4; ++j) {
            shortx8 sv = *(const shortx8*)&Sraw[r][j * 256 + l * 8];
            shortx8 ev;
            #pragma unroll
            for (int e = 0; e < 8; ++e) {
                float x = __expf(bf2f((unsigned short)sv[e]) - mx);  // exp(-inf)=0
                sum += x;
                ev[e] = (short)f2bf(x);
            }
            *(shortx8*)&Sraw[r][j * 256 + l * 8] = ev;
        }
        #pragma unroll
        for (int off = 16; off; off >>= 1) sum += __shfl_xor(sum, off, 32);
        if (l == 0) invs[r] = 1.0f / sum;
    }
    __syncthreads();

    // ---- Pass 3: O = (E V). m-range split across wave halves.
    // Dual accumulators: halve the serial MFMA chain; unroll keeps >=4
    // V-loads (L2) in flight against it.
    const int hm = w >> 2;            // m-half 0/1
    const int c  = (w & 3) * 16;      // output col slice
    floatx4 accA = {0.f, 0.f, 0.f, 0.f};
    floatx4 accB = {0.f, 0.f, 0.f, 0.f};
    const unsigned short* vcol = vbase + (size_t)(c + ln) * SEQ;
    #pragma unroll 4
    for (int it = 0; it < 16; it += 2) {
        const int kk0 = hm * 512 + (it >> 1) * 64 + qd * 8;
        const int kk1 = kk0 + 32;
        shortx8 af0  = *(const shortx8*)&Sraw[ln][kk0];
        shortx8 bf0  = *(const shortx8*)(vcol + kk0);
        shortx8 af1  = *(const shortx8*)&Sraw[ln][kk1];
        shortx8 bf1  = *(const shortx8*)(vcol + kk1);
        accA = __builtin_amdgcn_mfma_f32_16x16x32_bf16(af0, bf0, accA, 0, 0, 0);
        accB = __builtin_amdgcn_mfma_f32_16x16x32_bf16(af1, bf1, accB, 0, 0, 0);
    }
    floatx4 acco;
    acco[0] = accA[0] + accB[0];
    acco[1] = accA[1] + accB[1];
    acco[2] = accA[2] + accB[2];
    acco[3] = accA[3] + accB[3];

    if (hm == 1) {
        #pragma unroll
        for (int r = 0; r < 4; ++r) Opart[qd * 4 + r][c + ln] = acco[r];
    }
    __syncthreads();

    // ---- Tail: ALL global stores after the last barrier (no barrier ever
    // waits on the store burst; drain overlaps other blocks). ----
    if (hm == 0) {
        #pragma unroll
        for (int r = 0; r < 4; ++r) {
            int row = qd * 4 + r;
            float ov = (acco[r] + Opart[row][c + ln]) * invs[row];
            __builtin_nontemporal_store(
                ov, out + ((size_t)(b * SEQ + n0 + row)) * CH + h * DH + c + ln);
        }
    }
    {
        float* prow = pout + ((size_t)((h * BATCH + b) * SEQ + n0)) * SEQ;
        #pragma unroll
        for (int i = 0; i < RB; ++i) {
            const float inv = invs[i];
            unsigned pk = *(const unsigned*)&Sraw[i][t * 2];
            floatx2 pv = { bf2f((unsigned short)(pk & 0xFFFFu)) * inv,
                           bf2f((unsigned short)(pk >> 16)) * inv };
            __builtin_nontemporal_store(
                pv, (floatx2*)(prow + (size_t)i * SEQ + t * 2));
        }
    }
}

extern "C" void kernel_launch(void* const* d_in, const int* in_sizes, int n_in,
                              void* d_out, int out_size, void* d_ws, size_t ws_size,
                              hipStream_t stream) {
    const float* q    = (const float*)d_in[0];
    const float* k    = (const float*)d_in[1];
    const float* v    = (const float*)d_in[2];
    const void*  mask = d_in[3];
    const float* dis  = (const float*)d_in[4];
    float* out  = (float*)d_out;
    float* pout = out + (size_t)BATCH * SEQ * CH;   // p_attn after out

    // workspace: qb | kb | vt (each 2M bf16 = 4 MB) | pm (1 MB) => 13 MB
    unsigned short* qb  = (unsigned short*)d_ws;
    unsigned short* kbw = qb  + (size_t)BATCH * SEQ * CH;
    unsigned short* vtw = kbw + (size_t)BATCH * SEQ * CH;
    unsigned*       pmw = (unsigned*)(vtw + (size_t)BATCH * SEQ * CH);
    (void)ws_size;

    prep<<<3584, 256, 0, stream>>>(q, k, v, mask, qb, kbw, vtw, pmw);
    attn_mfma<<<HEADS * BATCH * (SEQ / RB), NTHR, 0, stream>>>(
        qb, kbw, vtw, pmw, dis, out, pout);
}